// Round 12
// baseline (361.888 us; speedup 1.0000x reference)
//
#include <hip/hip_runtime.h>
#include <math.h>

// ---------- types ----------
typedef __bf16 bf16x8 __attribute__((ext_vector_type(8)));
typedef float  f32x4  __attribute__((ext_vector_type(4)));

#define QCHUNK 128
#define NCHUNK 16
#define SLD 136              // LDS row stride (bf16 elems) for 128-wide arrays

__device__ __forceinline__ float bf2f(unsigned short u) {
    union { unsigned int i; float f; } v; v.i = ((unsigned int)u) << 16; return v.f;
}
__device__ __forceinline__ unsigned short f2bf(float f) {
    union { float f; unsigned int i; } v; v.f = f;
    unsigned int x = v.i;
    unsigned int r = (x + 0x7FFFu + ((x >> 16) & 1u)) >> 16;
    return (unsigned short)r;
}
__device__ __forceinline__ uint4 pack8(float4 a, float4 b) {
    uint4 r;
    r.x = (unsigned)f2bf(a.x) | ((unsigned)f2bf(a.y) << 16);
    r.y = (unsigned)f2bf(a.z) | ((unsigned)f2bf(a.w) << 16);
    r.z = (unsigned)f2bf(b.x) | ((unsigned)f2bf(b.y) << 16);
    r.w = (unsigned)f2bf(b.z) | ((unsigned)f2bf(b.w) << 16);
    return r;
}
__device__ __forceinline__ void load_lds16(const void* g, void* l) {
    __builtin_amdgcn_global_load_lds((const __attribute__((address_space(1))) void*)g,
                                     (__attribute__((address_space(3))) void*)l,
                                     16, 0, 0);
}

// ---------- convert: x -> x_bf, w_in rows [0,3328) -> w_in_bf, w_out -> w_out_bf ----------
__global__ __launch_bounds__(256)
void convert_kernel(const float* __restrict__ x, const float* __restrict__ w_in,
                    const float* __restrict__ w_out,
                    unsigned short* __restrict__ x_bf, unsigned short* __restrict__ w_in_bf,
                    unsigned short* __restrict__ w_out_bf) {
    int idx = blockIdx.x * 256 + threadIdx.x;      // 8 elems each
    const int NX  = 8192 * 768 / 8;                // 786432
    const int NW1 = 3328 * 768 / 8;                // 319488 (13x256 tiles, all real)
    const int NW2 = 768 * 1536 / 8;                // 147456
    if (idx < NX) {
        const float* s = x + (size_t)idx * 8;
        *(uint4*)(x_bf + (size_t)idx * 8) = pack8(*(const float4*)s, *(const float4*)(s + 4));
    } else if (idx < NX + NW1) {
        int j = idx - NX;
        const float* s = w_in + (size_t)j * 8;
        *(uint4*)(w_in_bf + (size_t)j * 8) = pack8(*(const float4*)s, *(const float4*)(s + 4));
    } else if (idx < NX + NW1 + NW2) {
        int j = idx - NX - NW1;
        const float* s = w_out + (size_t)j * 8;
        *(uint4*)(w_out_bf + (size_t)j * 8) = pack8(*(const float4*)s, *(const float4*)(s + 4));
    }
}

// ---------- 256x256 pipelined GEMM: Out[m,n] = sum_k A[m,k]*Bw[n,k], bf16 out ----------
// (R6/R9-verified schedule.) N = 3328 = 13x256 exactly.
__global__ __launch_bounds__(512)
void gemm_8phase(const unsigned short* __restrict__ A,
                 const unsigned short* __restrict__ Bw,
                 unsigned short* __restrict__ Out,
                 int ldo, int K) {
    extern __shared__ __align__(16) char smem[];

    const int tid = threadIdx.x;
    const int bid = blockIdx.x;
    // XCD-chunked: 416 = 8 XCDs x 52; n-fastest within chunk
    const int xcd = bid & 7, local = bid >> 3;
    const int mt = xcd * 4 + local / 13;       // 4 m-tiles per XCD
    const int nt = local % 13;
    const int m0 = mt * 256, n0 = nt * 256;

    const int wave = tid >> 6, lane = tid & 63;
    const int wr = wave >> 2, wc = wave & 3;
    const int lr = lane & 15, q = lane >> 4;

    const int gl   = (lr & 7) << 4;            // row-granule XOR bits (bits 4-6)
    const int arow = wr * 128 + lr;            // + m*16
    const int brow = wc * 64 + lr;             // + n*16
    const int colq = q << 4;                   // + kh*64, then ^ gl

    const int srow  = tid >> 3;                // 0..63
    const int sslot = (tid & 7) ^ (srow & 7);
    const unsigned short* ga = A  + (size_t)(m0 + srow) * K + sslot * 8;
    const unsigned short* gb = Bw + (size_t)(n0 + srow) * K + sslot * 8;
    char* sAd = smem +         (size_t)tid * 16;
    char* sBd = smem + 65536 + (size_t)tid * 16;
    const size_t gstep = (size_t)64 * K;

    const int NT = K >> 6;                     // 12
    f32x4 acc[8][4] = {};

    #pragma unroll
    for (int i = 0; i < 4; ++i) {
        load_lds16(ga + (size_t)i * gstep, sAd + i * 8192);
        load_lds16(gb + (size_t)i * gstep, sBd + i * 8192);
    }

    for (int t = 0; t < NT; ++t) {
        const int d = t & 1;
        const bool more = (t + 1 < NT);
        if (more) {
            const size_t kg = (size_t)(t + 1) * 64;
            const int ld = (d ^ 1) * 32768;
            #pragma unroll
            for (int i = 0; i < 4; ++i) {
                load_lds16(ga + kg + (size_t)i * gstep, sAd + ld + i * 8192);
                load_lds16(gb + kg + (size_t)i * gstep, sBd + ld + i * 8192);
            }
            asm volatile("s_waitcnt vmcnt(8)" ::: "memory");
        } else {
            asm volatile("s_waitcnt vmcnt(0)" ::: "memory");
        }
        __builtin_amdgcn_s_barrier();

        const char* pa = smem +         d * 32768;
        const char* pb = smem + 65536 + d * 32768;
        #pragma unroll
        for (int kh = 0; kh < 2; ++kh) {
            const int col = ((kh << 6) | colq) ^ gl;
            bf16x8 af[8], bfr[4];
            #pragma unroll
            for (int m = 0; m < 8; ++m)
                af[m] = *(const bf16x8*)(pa + (arow + m * 16) * 128 + col);
            #pragma unroll
            for (int n = 0; n < 4; ++n)
                bfr[n] = *(const bf16x8*)(pb + (brow + n * 16) * 128 + col);

            __builtin_amdgcn_s_setprio(1);
            #pragma unroll
            for (int m = 0; m < 8; ++m)
                #pragma unroll
                for (int n = 0; n < 4; ++n)
                    acc[m][n] = __builtin_amdgcn_mfma_f32_16x16x32_bf16(af[m], bfr[n], acc[m][n], 0, 0, 0);
            __builtin_amdgcn_s_setprio(0);
        }
        __builtin_amdgcn_s_barrier();
    }

    #pragma unroll
    for (int m = 0; m < 8; ++m) {
        #pragma unroll
        for (int r = 0; r < 4; ++r) {
            int row = m0 + wr * 128 + m * 16 + q * 4 + r;
            #pragma unroll
            for (int n = 0; n < 4; ++n) {
                int col = n0 + wc * 64 + n * 16 + lr;
                Out[(size_t)row * ldo + col] = f2bf(acc[m][n][r]);
            }
        }
    }
}

// ---------- out_proj GEMM: Out[m,n] = sum_k A[m,k]*Bw[n,k] + Resid, f32 out ----------
__global__ __launch_bounds__(512)
void gemm_out(const unsigned short* __restrict__ A,
              const unsigned short* __restrict__ Bw,
              float* __restrict__ Out, const float* __restrict__ Resid,
              int lda) {
    extern __shared__ __align__(16) char smem[];
    const int K = 1536, Nn = 768;

    const int tid = threadIdx.x;
    const int bid = blockIdx.x;
    const int xcd = bid & 7, local = bid >> 3;
    const int mt = xcd * 8 + local / 6;        // 0..63
    const int nt = local % 6;                  // 0..5
    const int m0 = mt * 128, n0 = nt * 128;

    const int wave = tid >> 6, lane = tid & 63;
    const int wr = wave >> 2, wc = wave & 3;
    const int lr = lane & 15, q = lane >> 4;

    const int gl   = (lr & 7) << 4;
    const int arow = wr * 64 + lr;             // + m*16
    const int brow = wc * 32 + lr;             // + n*16
    const int colq = q << 4;

    const int srow  = tid >> 3;                // 0..63
    const int sslot = (tid & 7) ^ (srow & 7);
    const unsigned short* ga = A  + (size_t)(m0 + srow) * lda + sslot * 8;
    const unsigned short* gb = Bw + (size_t)(n0 + srow) * K   + sslot * 8;
    char* sAd = smem +         (size_t)tid * 16;
    char* sBd = smem + 32768 + (size_t)tid * 16;
    const size_t gstep_a = (size_t)64 * lda;
    const size_t gstep_b = (size_t)64 * K;

    f32x4 acc[4][2] = {};

    #pragma unroll
    for (int i = 0; i < 2; ++i) {
        load_lds16(ga + (size_t)i * gstep_a, sAd + i * 8192);
        load_lds16(gb + (size_t)i * gstep_b, sBd + i * 8192);
    }

    const int NT = K >> 6;   // 24
    for (int t = 0; t < NT; ++t) {
        const int d = t & 1;
        const bool more = (t + 1 < NT);
        if (more) {
            const size_t kg = (size_t)(t + 1) * 64;
            const int ld = (d ^ 1) * 16384;
            #pragma unroll
            for (int i = 0; i < 2; ++i) {
                load_lds16(ga + kg + (size_t)i * gstep_a, sAd + ld + i * 8192);
                load_lds16(gb + kg + (size_t)i * gstep_b, sBd + ld + i * 8192);
            }
            asm volatile("s_waitcnt vmcnt(4)" ::: "memory");
        } else {
            asm volatile("s_waitcnt vmcnt(0)" ::: "memory");
        }
        __builtin_amdgcn_s_barrier();

        const char* pa = smem +         d * 16384;
        const char* pb = smem + 32768 + d * 16384;
        #pragma unroll
        for (int kh = 0; kh < 2; ++kh) {
            const int col = ((kh << 6) | colq) ^ gl;
            bf16x8 af[4], bfr[2];
            #pragma unroll
            for (int m = 0; m < 4; ++m)
                af[m] = *(const bf16x8*)(pa + (arow + m * 16) * 128 + col);
            #pragma unroll
            for (int n = 0; n < 2; ++n)
                bfr[n] = *(const bf16x8*)(pb + (brow + n * 16) * 128 + col);

            __builtin_amdgcn_s_setprio(1);
            #pragma unroll
            for (int m = 0; m < 4; ++m)
                #pragma unroll
                for (int n = 0; n < 2; ++n)
                    acc[m][n] = __builtin_amdgcn_mfma_f32_16x16x32_bf16(af[m], bfr[n], acc[m][n], 0, 0, 0);
            __builtin_amdgcn_s_setprio(0);
        }
        __builtin_amdgcn_s_barrier();
    }

    #pragma unroll
    for (int m = 0; m < 4; ++m) {
        #pragma unroll
        for (int r = 0; r < 4; ++r) {
            int row = m0 + wr * 64 + m * 16 + q * 4 + r;
            #pragma unroll
            for (int n = 0; n < 2; ++n) {
                int col = n0 + wc * 32 + n * 16 + lr;
                Out[(size_t)row * Nn + col] = acc[m][n][r] + Resid[(size_t)row * Nn + col];
            }
        }
    }
}

// ---------- fused conv(4)+silu+layout ----------
__global__ __launch_bounds__(256)
void conv_fused_kernel(const unsigned short* __restrict__ zx,
                       const float* __restrict__ cw, const float* __restrict__ cb,
                       unsigned short* __restrict__ xT, unsigned short* __restrict__ bT,
                       unsigned short* __restrict__ Brow, unsigned short* __restrict__ Crow) {
    __shared__ unsigned short outt[64][66];
    __shared__ float cwl[64][4];
    __shared__ float cbl[64];

    int blk = blockIdx.x;
    int cht = blk % 28;
    int tt  = (blk / 28) % 32;
    int b   = blk / (28 * 32);
    int ch0 = cht * 64, t0 = tt * 64;
    int tid = threadIdx.x;
    int tx = tid & 63, ty = tid >> 6;

    if (tid < 64) cbl[tid] = cb[ch0 + tid];
    cwl[tid >> 2][tid & 3] = cw[(ch0 + (tid >> 2)) * 4 + (tid & 3)];
    __syncthreads();

    const unsigned short* zp = zx + (size_t)(b * 2048) * 3352 + 1536 + ch0 + tx;
    float w0 = cwl[tx][0], w1 = cwl[tx][1], w2 = cwl[tx][2], w3 = cwl[tx][3];
    float bias = cbl[tx];
    int tg = t0 + ty * 16;                 // first output t for this thread
    float r0 = (tg >= 3) ? bf2f(zp[(size_t)(tg - 3) * 3352]) : 0.f;
    float r1 = (tg >= 2) ? bf2f(zp[(size_t)(tg - 2) * 3352]) : 0.f;
    float r2 = (tg >= 1) ? bf2f(zp[(size_t)(tg - 1) * 3352]) : 0.f;
    #pragma unroll
    for (int k = 0; k < 16; ++k) {
        float cur = bf2f(zp[(size_t)(tg + k) * 3352]);
        float a = bias + r0 * w0 + r1 * w1 + r2 * w2 + cur * w3;
        a = a / (1.f + expf(-a));          // silu
        outt[ty * 16 + k][tx] = f2bf(a);
        r0 = r1; r1 = r2; r2 = cur;
    }
    __syncthreads();

    if (ch0 < 1536) {
        unsigned short* dst = xT + ((size_t)(b * 1536 + ch0)) * 2048 + t0;
        #pragma unroll
        for (int k = 0; k < 16; ++k) {
            int chl = ty * 16 + k;
            dst[(size_t)chl * 2048 + tx] = outt[tx][chl];
        }
    } else if (ch0 < 1664) {
        int n0 = ch0 - 1536;
        unsigned short* dstT = bT + ((size_t)(b * 128 + n0)) * 2048 + t0;
        #pragma unroll
        for (int k = 0; k < 16; ++k) {
            int chl = ty * 16 + k;
            dstT[(size_t)chl * 2048 + tx] = outt[tx][chl];
        }
        unsigned short* dstR = Brow + ((size_t)(b * 2048 + t0)) * 128 + n0;
        int tl = tid >> 3, c8 = (tid & 7) << 3;
        #pragma unroll
        for (int it = 0; it < 2; ++it) {
            int t = tl + it * 32;
            unsigned short tmp[8];
            #pragma unroll
            for (int jj = 0; jj < 8; ++jj) tmp[jj] = outt[t][c8 + jj];
            *(uint4*)(dstR + (size_t)t * 128 + c8) = *(uint4*)tmp;
        }
    } else {
        int n0 = ch0 - 1664;
        unsigned short* dstR = Crow + ((size_t)(b * 2048 + t0)) * 128 + n0;
        int tl = tid >> 3, c8 = (tid & 7) << 3;
        #pragma unroll
        for (int it = 0; it < 2; ++it) {
            int t = tl + it * 32;
            unsigned short tmp[8];
            #pragma unroll
            for (int jj = 0; jj < 8; ++jj) tmp[jj] = outt[t][c8 + jj];
            *(uint4*)(dstR + (size_t)t * 128 + c8) = *(uint4*)tmp;
        }
    }
}

// ---------- dt: 1024 blocks x 256 thr, 8 rows/block; x + w_dt staged in LDS; full f32 ----------
__global__ __launch_bounds__(256)
void dt_kernel(const float* __restrict__ x, const float* __restrict__ w_in,
               const float* __restrict__ dt_bias, const float* __restrict__ A_log,
               float2* __restrict__ dtdA) {
    __shared__ float xs[8 * 768];        // 24 KB
    __shared__ float wsh[24 * 257];      // 24.1 KB
    const int tid = threadIdx.x;
    const int row0 = blockIdx.x * 8;

    for (int i = tid; i < 8 * 768 / 4; i += 256)
        *(float4*)(xs + i * 4) = *(const float4*)(x + (size_t)row0 * 768 + (size_t)i * 4);

    const int rr = tid / 24, hh = tid - rr * 24;   // valid for tid < 192
    float acc0 = 0.f, acc1 = 0.f, acc2 = 0.f, acc3 = 0.f;

    for (int kc = 0; kc < 3; ++kc) {
        __syncthreads();
        for (int i = tid; i < 24 * 256; i += 256) {
            int h = i >> 8, kk = i & 255;
            wsh[h * 257 + kk] = w_in[(size_t)(3328 + h) * 768 + kc * 256 + kk];
        }
        __syncthreads();
        if (tid < 192) {
            const float* xp = xs + rr * 768 + kc * 256;
            const float* wp = wsh + hh * 257;
            #pragma unroll 16
            for (int kk = 0; kk < 256; kk += 4) {
                acc0 += xp[kk]     * wp[kk];
                acc1 += xp[kk + 1] * wp[kk + 1];
                acc2 += xp[kk + 2] * wp[kk + 2];
                acc3 += xp[kk + 3] * wp[kk + 3];
            }
        }
    }
    if (tid < 192) {
        float v = (acc0 + acc1) + (acc2 + acc3) + dt_bias[hh];
        float dt = (v > 20.f) ? v : log1pf(expf(v));
        float A = -expf(A_log[hh]);
        dtdA[(size_t)(row0 + rr) * 24 + hh] = make_float2(dt, dt * A);   // (dt, log dA)
    }
}

// ---------- SSD local kernel: per (b,h,chunk): G -> M -> Y, s_out ----------
__global__ __launch_bounds__(256)
void ssd_local_kernel(const unsigned short* __restrict__ Brow,
                      const unsigned short* __restrict__ Crow,
                      const float2* __restrict__ dtdA,
                      const unsigned short* __restrict__ xT,
                      const unsigned short* __restrict__ bT,
                      const float* __restrict__ Dh,
                      unsigned short* __restrict__ yb,
                      unsigned short* __restrict__ sst,
                      float* __restrict__ Pbuf) {
    extern __shared__ __align__(16) char smem[];
    __bf16* Bs  = (__bf16*)smem;                 // 128 x SLD; later Xt(0:17408)+Xtw(17408:34816)
    __bf16* Cs  = (__bf16*)(smem + 34816);       // 128 x SLD; later Ms
    float*  Lc  = (float*)(smem + 69632);        // 128
    float*  dtl = (float*)(smem + 70144);        // 128

    const int tid = threadIdx.x;
    const int c   = blockIdx.x & 15;
    const int bh  = blockIdx.x >> 4;
    const int b   = bh / 24, h = bh % 24;
    const int t0g = b * 2048 + c * QCHUNK;
    const int wave = tid >> 6, lane = tid & 63;
    const int lr = lane & 15, q = lane >> 4;

    for (int cc = tid; cc < 2048; cc += 256) {
        int r = cc >> 4, c8 = (cc & 15) << 3;
        *(uint4*)(Bs + r * SLD + c8) = *(const uint4*)(Brow + ((size_t)(t0g + r)) * 128 + c8);
        *(uint4*)(Cs + r * SLD + c8) = *(const uint4*)(Crow + ((size_t)(t0g + r)) * 128 + c8);
    }
    if (tid < 128) {
        float2 dd = dtdA[((size_t)t0g + tid) * 24 + h];
        dtl[tid] = dd.x;
        Lc[tid]  = dd.y;     // log dA
    }
    __syncthreads();
    // single-wave pair scan
    if (tid < 64) {
        float a0 = Lc[2 * tid], a1 = Lc[2 * tid + 1];
        float s = a0 + a1;
        #pragma unroll
        for (int d = 1; d < 64; d <<= 1) {
            float v = __shfl_up(s, d);
            if (tid >= d) s += v;
        }
        float ex = s - (a0 + a1);
        Lc[2 * tid]     = ex + a0;
        Lc[2 * tid + 1] = ex + a0 + a1;
    }
    __syncthreads();

    // P1: G = Cs . Bs^T
    const int wm = (wave & 1) * 64, wn = (wave >> 1) * 64;
    f32x4 g[4][4] = {};
    #pragma unroll
    for (int k0 = 0; k0 < 128; k0 += 32) {
        bf16x8 af[4], bfr[4];
        #pragma unroll
        for (int t = 0; t < 4; ++t) {
            af[t]  = *(const bf16x8*)(Cs + (wm + t * 16 + lr) * SLD + k0 + q * 8);
            bfr[t] = *(const bf16x8*)(Bs + (wn + t * 16 + lr) * SLD + k0 + q * 8);
        }
        #pragma unroll
        for (int ti = 0; ti < 4; ++ti)
            #pragma unroll
            for (int tj = 0; tj < 4; ++tj)
                g[ti][tj] = __builtin_amdgcn_mfma_f32_16x16x32_bf16(af[ti], bfr[tj], g[ti][tj], 0, 0, 0);
    }
    __syncthreads();

    // P5: masked scale -> Ms[t][tau]
    __bf16* Ms = Cs;
    {
        float lt_[4], dt_[4];
        #pragma unroll
        for (int tj = 0; tj < 4; ++tj) {
            int tau = wn + tj * 16 + lr;
            lt_[tj] = Lc[tau];
            dt_[tj] = dtl[tau];
        }
        #pragma unroll
        for (int ti = 0; ti < 4; ++ti) {
            #pragma unroll
            for (int r = 0; r < 4; ++r) {
                int t = wm + ti * 16 + q * 4 + r;
                float Lt = Lc[t];
                #pragma unroll
                for (int tj = 0; tj < 4; ++tj) {
                    int tau = wn + tj * 16 + lr;
                    float mv = (tau <= t) ? g[ti][tj][r] * expf(Lt - lt_[tj]) * dt_[tj] : 0.f;
                    unsigned short u = f2bf(mv);
                    Ms[t * SLD + tau] = *(__bf16*)&u;
                }
            }
        }
    }

    // P3: stage Xt[p][t] and Xtw[p][t]
    __bf16* Xt  = Bs;
    __bf16* Xtw = (__bf16*)(smem + 17408);
    {
        float LQ = Lc[127];
        const unsigned short* xTb = xT + ((size_t)(b * 1536 + h * 64)) * 2048 + c * QCHUNK;
        for (int cc = tid; cc < 1024; cc += 256) {
            int p = cc >> 4, c8 = (cc & 15) << 3;
            uint4 v = *(const uint4*)(xTb + (size_t)p * 2048 + c8);
            *(uint4*)(Xt + p * SLD + c8) = v;
            unsigned short uu[8] = {(unsigned short)(v.x & 0xFFFF), (unsigned short)(v.x >> 16),
                                    (unsigned short)(v.y & 0xFFFF), (unsigned short)(v.y >> 16),
                                    (unsigned short)(v.z & 0xFFFF), (unsigned short)(v.z >> 16),
                                    (unsigned short)(v.w & 0xFFFF), (unsigned short)(v.w >> 16)};
            float w0[8];
            #pragma unroll
            for (int jj = 0; jj < 8; ++jj) {
                int tau = c8 + jj;
                w0[jj] = bf2f(uu[jj]) * expf(LQ - Lc[tau]) * dtl[tau];
            }
            *(uint4*)(Xtw + p * SLD + c8) = pack8(make_float4(w0[0], w0[1], w0[2], w0[3]),
                                                  make_float4(w0[4], w0[5], w0[6], w0[7]));
        }
    }
    __syncthreads();

    // P4: s_out[n][p] = bT . Xtw^T
    {
        f32x4 so[2][4] = {};
        const unsigned short* bTb = bT + ((size_t)(b * 128)) * 2048 + c * QCHUNK;
        #pragma unroll
        for (int k0 = 0; k0 < 128; k0 += 32) {
            bf16x8 af[2], bfr[4];
            #pragma unroll
            for (int ti = 0; ti < 2; ++ti) {
                int n = wave * 32 + ti * 16 + lr;
                af[ti] = *(const bf16x8*)(bTb + (size_t)n * 2048 + k0 + q * 8);
            }
            #pragma unroll
            for (int tj = 0; tj < 4; ++tj)
                bfr[tj] = *(const bf16x8*)(Xtw + (tj * 16 + lr) * SLD + k0 + q * 8);
            #pragma unroll
            for (int ti = 0; ti < 2; ++ti)
                #pragma unroll
                for (int tj = 0; tj < 4; ++tj)
                    so[ti][tj] = __builtin_amdgcn_mfma_f32_16x16x32_bf16(af[ti], bfr[tj], so[ti][tj], 0, 0, 0);
        }
        unsigned short* sb = sst + ((size_t)(bh * NCHUNK + c)) * 8192;
        #pragma unroll
        for (int ti = 0; ti < 2; ++ti) {
            #pragma unroll
            for (int r = 0; r < 4; ++r) {
                int n = wave * 32 + ti * 16 + q * 4 + r;
                #pragma unroll
                for (int tj = 0; tj < 4; ++tj) {
                    int p = tj * 16 + lr;
                    sb[n * 64 + p] = f2bf(so[ti][tj][r]);
                }
            }
        }
        if (tid == 0) Pbuf[bh * NCHUNK + c] = expf(Lc[127]);
    }

    // P6: Y[t][p] = Ms . Xt^T  (+ D skip) -> bf16
    {
        f32x4 ya[2][4] = {};
        #pragma unroll
        for (int k0 = 0; k0 < 128; k0 += 32) {
            bf16x8 af[2], bfr[4];
            #pragma unroll
            for (int ti = 0; ti < 2; ++ti)
                af[ti] = *(const bf16x8*)(Ms + (wave * 32 + ti * 16 + lr) * SLD + k0 + q * 8);
            #pragma unroll
            for (int tj = 0; tj < 4; ++tj)
                bfr[tj] = *(const bf16x8*)(Xt + (tj * 16 + lr) * SLD + k0 + q * 8);
            #pragma unroll
            for (int ti = 0; ti < 2; ++ti)
                #pragma unroll
                for (int tj = 0; tj < 4; ++tj)
                    ya[ti][tj] = __builtin_amdgcn_mfma_f32_16x16x32_bf16(af[ti], bfr[tj], ya[ti][tj], 0, 0, 0);
        }
        float Dv = Dh[h];
        unsigned short* ybb = yb + (size_t)t0g * 1536 + h * 64;
        #pragma unroll
        for (int ti = 0; ti < 2; ++ti) {
            #pragma unroll
            for (int r = 0; r < 4; ++r) {
                int t = wave * 32 + ti * 16 + q * 4 + r;
                #pragma unroll
                for (int tj = 0; tj < 4; ++tj) {
                    int p = tj * 16 + lr;
                    __bf16 xb = Xt[p * SLD + t];
                    float xv = bf2f(*(unsigned short*)&xb);
                    ybb[(size_t)t * 1536 + p] = f2bf(ya[ti][tj][r] + Dv * xv);
                }
            }
        }
    }
}

// ---------- fused combine + SSD inter: per (bh, 32-p-half) persistent block ----------
// State s (combine-proven map: pl=tid&31, nb=tid>>5, n=nb+8i) lives in registers.
// Per chunk c=0..14: s = P[c]*s + sst[c]; St[p][n] <- s (bf16); stage Crow chunk c+1;
// MFMA Y[t][p] = C(c+1)[t,n] . St[p,n]; yb += exp(Lc_scan(c+1))*Y.  All 15 Lc scans
// precomputed wave-parallel.  Replaces combine_kernel + old ssd_inter (no sstT).
__global__ __launch_bounds__(256)
void ssd_inter_kernel(const unsigned short* __restrict__ Crow,
                      const float2* __restrict__ dtdA,
                      const unsigned short* __restrict__ sst,
                      const float* __restrict__ Pbuf,
                      unsigned short* __restrict__ yb) {
    __shared__ __align__(16) __bf16 Cs[128 * SLD];   // 34816 B
    __shared__ __align__(16) __bf16 St[32 * SLD];    // 8704 B
    __shared__ float LcA[15][128];                   // 7680 B  (~51 KB total)

    const int tid = threadIdx.x;
    const int blk = blockIdx.x;            // 192 = 96 bh x 2 p-halves
    const int bh = blk >> 1;
    const int ph = (blk & 1) * 32;
    const int b = bh / 24, h = bh % 24;
    const int wave = tid >> 6, lane = tid & 63;
    const int lr = lane & 15, q = lane >> 4;
    const int pl = tid & 31, nb = tid >> 5;

    // pre-scan Lc for chunks 1..15 (wave w handles cc = 1+w+4j)
    #pragma unroll
    for (int j = 0; j < 4; ++j) {
        int cc = 1 + wave + 4 * j;
        if (cc <= 15) {
            int tb = b * 2048 + cc * 128;
            float a0 = dtdA[(size_t)(tb + 2 * lane) * 24 + h].y;
            float a1 = dtdA[(size_t)(tb + 2 * lane + 1) * 24 + h].y;
            float s = a0 + a1;
            #pragma unroll
            for (int d = 1; d < 64; d <<= 1) {
                float v = __shfl_up(s, d);
                if (lane >= d) s += v;
            }
            float ex = s - (a0 + a1);
            LcA[cc - 1][2 * lane]     = ex + a0;
            LcA[cc - 1][2 * lane + 1] = ex + a0 + a1;
        }
    }

    const unsigned short* sb = sst + (size_t)bh * NCHUNK * 8192;
    const float* Pb = Pbuf + bh * NCHUNK;

    float s[16];
    #pragma unroll
    for (int i = 0; i < 16; ++i) s[i] = 0.f;

    for (int c = 0; c < 15; ++c) {
        const float Pc = Pb[c];
        const unsigned short* sc = sb + (size_t)c * 8192;
        #pragma unroll
        for (int i = 0; i < 16; ++i) {
            int n = nb + 8 * i;
            s[i] = Pc * s[i] + bf2f(sc[n * 64 + ph + pl]);   // state after chunk c
        }
        __syncthreads();                   // prev iter's MFMA reads of St/Cs done (also LcA ready)
        #pragma unroll
        for (int i = 0; i < 16; ++i) {
            int n = nb + 8 * i;
            unsigned short u = f2bf(s[i]);
            St[pl * SLD + n] = *(__bf16*)&u;
        }
        const int t0g = b * 2048 + (c + 1) * QCHUNK;
        for (int cc2 = tid; cc2 < 2048; cc2 += 256) {
            int r = cc2 >> 4, c8 = (cc2 & 15) << 3;
            *(uint4*)(Cs + r * SLD + c8) = *(const uint4*)(Crow + ((size_t)(t0g + r)) * 128 + c8);
        }
        __syncthreads();

        f32x4 ya[2][2] = {};
        #pragma unroll
        for (int k0 = 0; k0 < 128; k0 += 32) {
            bf16x8 af[2], bfr[2];
            #pragma unroll
            for (int ti = 0; ti < 2; ++ti)
                af[ti] = *(const bf16x8*)(Cs + (wave * 32 + ti * 16 + lr) * SLD + k0 + q * 8);
            #pragma unroll
            for (int tj = 0; tj < 2; ++tj)
                bfr[tj] = *(const bf16x8*)(St + (tj * 16 + lr) * SLD + k0 + q * 8);
            #pragma unroll
            for (int ti = 0; ti < 2; ++ti)
                #pragma unroll
                for (int tj = 0; tj < 2; ++tj)
                    ya[ti][tj] = __builtin_amdgcn_mfma_f32_16x16x32_bf16(af[ti], bfr[tj], ya[ti][tj], 0, 0, 0);
        }
        unsigned short* ybb = yb + (size_t)t0g * 1536 + h * 64 + ph;
        const float* Lcc = LcA[c];         // chunk c+1's scanned Lc
        #pragma unroll
        for (int ti = 0; ti < 2; ++ti) {
            #pragma unroll
            for (int r = 0; r < 4; ++r) {
                int t = wave * 32 + ti * 16 + q * 4 + r;
                float sc2 = expf(Lcc[t]);
                #pragma unroll
                for (int tj = 0; tj < 2; ++tj) {
                    int p = tj * 16 + lr;
                    unsigned short* yp = ybb + (size_t)t * 1536 + p;
                    *yp = f2bf(bf2f(*yp) + sc2 * ya[ti][tj][r]);
                }
            }
        }
    }
}

// ---------- gated RMSNorm: reads yb bf16, writes bf16 into zx cols [1536,3072) ----------
__global__ __launch_bounds__(256)
void norm_kernel(const unsigned short* __restrict__ yb,
                 unsigned short* __restrict__ zx,
                 const float* __restrict__ nw) {
    int row = blockIdx.x;
    const unsigned short* yr = yb + (size_t)row * 1536;
    unsigned short* zr = zx + (size_t)row * 3352;
    int tid = threadIdx.x;
    float u[6];
    float ss = 0.f;
    #pragma unroll
    for (int i = 0; i < 6; ++i) {
        int c = tid + i * 256;
        float z = bf2f(zr[c]);
        float uu = bf2f(yr[c]) * (z / (1.f + expf(-z)));
        u[i] = uu;
        ss += uu * uu;
    }
    #pragma unroll
    for (int m = 1; m < 64; m <<= 1) ss += __shfl_xor(ss, m);
    __shared__ float red[4];
    if ((tid & 63) == 0) red[tid >> 6] = ss;
    __syncthreads();
    float tot = red[0] + red[1] + red[2] + red[3];
    float inv = rsqrtf(tot * (1.f / 1536.f) + 1e-5f);
    #pragma unroll
    for (int i = 0; i < 6; ++i) {
        int c = tid + i * 256;
        zr[1536 + c] = f2bf(u[i] * inv * nw[c]);
    }
}

// ---------- launch ----------
extern "C" void kernel_launch(void* const* d_in, const int* in_sizes, int n_in,
                              void* d_out, int out_size, void* d_ws, size_t ws_size,
                              hipStream_t stream) {
    const float* x       = (const float*)d_in[0];
    const float* w_in    = (const float*)d_in[1];
    const float* conv_w  = (const float*)d_in[2];
    const float* conv_b  = (const float*)d_in[3];
    const float* dt_bias = (const float*)d_in[4];
    const float* A_log   = (const float*)d_in[5];
    const float* Dp      = (const float*)d_in[6];
    const float* nw      = (const float*)d_in[7];
    const float* w_out   = (const float*)d_in[8];
    float* out = (float*)d_out;

    char* ws = (char*)d_ws;
    const size_t off_zx   = 0;                        // 8192*3352 bf16 = 54,919,168
    const size_t off_A    = off_zx + 54919168;        // region A (58,720,256 reserved)
    const size_t off_xT   = off_A;                    // 25,165,824
    const size_t off_bT   = off_A + 25165824;         // 2,097,152
    const size_t off_Brow = off_A + 27262976;         // 2,097,152
    const size_t off_Crow = off_A + 29360128;         // 2,097,152
    const size_t off_dtdA = off_A + 58720256;         // 1,572,864
    const size_t off_y    = off_dtdA + 1572864;       // 50,331,648 reserved: yb bf16 (25MB) + w_out_bf; x_bf aliases head
    const size_t off_sst  = off_y + 50331648;         // 25,165,824 (w_in_bf aliases head)
    const size_t off_P    = off_sst + 25165824;       // 6,144

    unsigned short* zx   = (unsigned short*)(ws + off_zx);
    unsigned short* xT   = (unsigned short*)(ws + off_xT);
    unsigned short* bT   = (unsigned short*)(ws + off_bT);
    unsigned short* Brow = (unsigned short*)(ws + off_Brow);
    unsigned short* Crow = (unsigned short*)(ws + off_Crow);
    float2* dtdA = (float2*)(ws + off_dtdA);
    unsigned short* yb   = (unsigned short*)(ws + off_y);
    unsigned short* sst  = (unsigned short*)(ws + off_sst);
    float* Pbuf = (float*)(ws + off_P);

    // transient aliases (dead regions at time of use)
    unsigned short* x_bf     = (unsigned short*)(ws + off_y);              // gemm1 only (before yb written)
    unsigned short* w_out_bf = (unsigned short*)(ws + off_y + 25165824);   // second half of off_y region
    unsigned short* w_in_bf  = (unsigned short*)(ws + off_sst);            // gemm1 only (before sst written)

    static bool attr_set = false;
    if (!attr_set) {
        hipFuncSetAttribute((const void*)ssd_local_kernel,
                            hipFuncAttributeMaxDynamicSharedMemorySize, 70656);
        hipFuncSetAttribute((const void*)gemm_8phase,
                            hipFuncAttributeMaxDynamicSharedMemorySize, 131072);
        hipFuncSetAttribute((const void*)gemm_out,
                            hipFuncAttributeMaxDynamicSharedMemorySize, 65536);
        attr_set = true;
    }

    // 0. convert x, w_in rows [0,3328), w_out -> bf16 (one launch)
    convert_kernel<<<4896, 256, 0, stream>>>(x, w_in, w_out, x_bf, w_in_bf, w_out_bf);
    // 1. in_proj (M=8192, N=3328 = 13x256 exactly), out stride 3352
    gemm_8phase<<<416, 512, 131072, stream>>>(x_bf, w_in_bf, zx, 3352, 768);
    // 2. fused conv + silu + layout
    conv_fused_kernel<<<3584, 256, 0, stream>>>(zx, conv_w, conv_b, xT, bT, Brow, Crow);
    // 3. dt / log-dA (full f32) — LDS-staged, 8 rows/block
    dt_kernel<<<1024, 256, 0, stream>>>(x, w_in, dt_bias, A_log, dtdA);
    // 4. SSD local (yb bf16)
    ssd_local_kernel<<<1536, 256, 70656, stream>>>(Brow, Crow, dtdA, xT, bT, Dp, yb, sst, Pbuf);
    // 5. fused combine + SSD inter: register-resident state, no sstT round-trip
    ssd_inter_kernel<<<192, 256, 0, stream>>>(Crow, dtdA, sst, Pbuf, yb);
    // 6. gated RMSNorm (yb bf16 in) -> bf16 into zx cols [1536,3072)
    norm_kernel<<<8192, 256, 0, stream>>>(yb, zx, nw);
    // 7. out_proj + residual
    gemm_out<<<384, 512, 65536, stream>>>(zx + 1536, w_out_bf, out, x, 3352);
}

// Round 13
// 318.898 us; speedup vs baseline: 1.1348x; 1.1348x over previous
//
#include <hip/hip_runtime.h>
#include <math.h>

// ---------- types ----------
typedef __bf16 bf16x8 __attribute__((ext_vector_type(8)));
typedef float  f32x4  __attribute__((ext_vector_type(4)));

#define QCHUNK 128
#define NCHUNK 16
#define SLD 136              // LDS row stride (bf16 elems) for 128-wide arrays

__device__ __forceinline__ float bf2f(unsigned short u) {
    union { unsigned int i; float f; } v; v.i = ((unsigned int)u) << 16; return v.f;
}
__device__ __forceinline__ unsigned short f2bf(float f) {
    union { float f; unsigned int i; } v; v.f = f;
    unsigned int x = v.i;
    unsigned int r = (x + 0x7FFFu + ((x >> 16) & 1u)) >> 16;
    return (unsigned short)r;
}
__device__ __forceinline__ uint4 pack8(float4 a, float4 b) {
    uint4 r;
    r.x = (unsigned)f2bf(a.x) | ((unsigned)f2bf(a.y) << 16);
    r.y = (unsigned)f2bf(a.z) | ((unsigned)f2bf(a.w) << 16);
    r.z = (unsigned)f2bf(b.x) | ((unsigned)f2bf(b.y) << 16);
    r.w = (unsigned)f2bf(b.z) | ((unsigned)f2bf(b.w) << 16);
    return r;
}
__device__ __forceinline__ void load_lds16(const void* g, void* l) {
    __builtin_amdgcn_global_load_lds((const __attribute__((address_space(1))) void*)g,
                                     (__attribute__((address_space(3))) void*)l,
                                     16, 0, 0);
}

// ---------- convert: x -> x_bf, w_in rows [0,3328) -> w_in_bf, w_out -> w_out_bf ----------
__global__ __launch_bounds__(256)
void convert_kernel(const float* __restrict__ x, const float* __restrict__ w_in,
                    const float* __restrict__ w_out,
                    unsigned short* __restrict__ x_bf, unsigned short* __restrict__ w_in_bf,
                    unsigned short* __restrict__ w_out_bf) {
    int idx = blockIdx.x * 256 + threadIdx.x;      // 8 elems each
    const int NX  = 8192 * 768 / 8;                // 786432
    const int NW1 = 3328 * 768 / 8;                // 319488 (13x256 tiles, all real)
    const int NW2 = 768 * 1536 / 8;                // 147456
    if (idx < NX) {
        const float* s = x + (size_t)idx * 8;
        *(uint4*)(x_bf + (size_t)idx * 8) = pack8(*(const float4*)s, *(const float4*)(s + 4));
    } else if (idx < NX + NW1) {
        int j = idx - NX;
        const float* s = w_in + (size_t)j * 8;
        *(uint4*)(w_in_bf + (size_t)j * 8) = pack8(*(const float4*)s, *(const float4*)(s + 4));
    } else if (idx < NX + NW1 + NW2) {
        int j = idx - NX - NW1;
        const float* s = w_out + (size_t)j * 8;
        *(uint4*)(w_out_bf + (size_t)j * 8) = pack8(*(const float4*)s, *(const float4*)(s + 4));
    }
}

// ---------- 256x256 pipelined GEMM: Out[m,n] = sum_k A[m,k]*Bw[n,k], bf16 out ----------
__global__ __launch_bounds__(512)
void gemm_8phase(const unsigned short* __restrict__ A,
                 const unsigned short* __restrict__ Bw,
                 unsigned short* __restrict__ Out,
                 int ldo, int K) {
    extern __shared__ __align__(16) char smem[];

    const int tid = threadIdx.x;
    const int bid = blockIdx.x;
    const int xcd = bid & 7, local = bid >> 3;
    const int mt = xcd * 4 + local / 13;       // 4 m-tiles per XCD
    const int nt = local % 13;
    const int m0 = mt * 256, n0 = nt * 256;

    const int wave = tid >> 6, lane = tid & 63;
    const int wr = wave >> 2, wc = wave & 3;
    const int lr = lane & 15, q = lane >> 4;

    const int gl   = (lr & 7) << 4;
    const int arow = wr * 128 + lr;
    const int brow = wc * 64 + lr;
    const int colq = q << 4;

    const int srow  = tid >> 3;
    const int sslot = (tid & 7) ^ (srow & 7);
    const unsigned short* ga = A  + (size_t)(m0 + srow) * K + sslot * 8;
    const unsigned short* gb = Bw + (size_t)(n0 + srow) * K + sslot * 8;
    char* sAd = smem +         (size_t)tid * 16;
    char* sBd = smem + 65536 + (size_t)tid * 16;
    const size_t gstep = (size_t)64 * K;

    const int NT = K >> 6;                     // 12
    f32x4 acc[8][4] = {};

    #pragma unroll
    for (int i = 0; i < 4; ++i) {
        load_lds16(ga + (size_t)i * gstep, sAd + i * 8192);
        load_lds16(gb + (size_t)i * gstep, sBd + i * 8192);
    }

    for (int t = 0; t < NT; ++t) {
        const int d = t & 1;
        const bool more = (t + 1 < NT);
        if (more) {
            const size_t kg = (size_t)(t + 1) * 64;
            const int ld = (d ^ 1) * 32768;
            #pragma unroll
            for (int i = 0; i < 4; ++i) {
                load_lds16(ga + kg + (size_t)i * gstep, sAd + ld + i * 8192);
                load_lds16(gb + kg + (size_t)i * gstep, sBd + ld + i * 8192);
            }
            asm volatile("s_waitcnt vmcnt(8)" ::: "memory");
        } else {
            asm volatile("s_waitcnt vmcnt(0)" ::: "memory");
        }
        __builtin_amdgcn_s_barrier();

        const char* pa = smem +         d * 32768;
        const char* pb = smem + 65536 + d * 32768;
        #pragma unroll
        for (int kh = 0; kh < 2; ++kh) {
            const int col = ((kh << 6) | colq) ^ gl;
            bf16x8 af[8], bfr[4];
            #pragma unroll
            for (int m = 0; m < 8; ++m)
                af[m] = *(const bf16x8*)(pa + (arow + m * 16) * 128 + col);
            #pragma unroll
            for (int n = 0; n < 4; ++n)
                bfr[n] = *(const bf16x8*)(pb + (brow + n * 16) * 128 + col);

            __builtin_amdgcn_s_setprio(1);
            #pragma unroll
            for (int m = 0; m < 8; ++m)
                #pragma unroll
                for (int n = 0; n < 4; ++n)
                    acc[m][n] = __builtin_amdgcn_mfma_f32_16x16x32_bf16(af[m], bfr[n], acc[m][n], 0, 0, 0);
            __builtin_amdgcn_s_setprio(0);
        }
        __builtin_amdgcn_s_barrier();
    }

    #pragma unroll
    for (int m = 0; m < 8; ++m) {
        #pragma unroll
        for (int r = 0; r < 4; ++r) {
            int row = m0 + wr * 128 + m * 16 + q * 4 + r;
            #pragma unroll
            for (int n = 0; n < 4; ++n) {
                int col = n0 + wc * 64 + n * 16 + lr;
                Out[(size_t)row * ldo + col] = f2bf(acc[m][n][r]);
            }
        }
    }
}

// ---------- out_proj GEMM: Out[m,n] = sum_k A[m,k]*Bw[n,k] + Resid, f32 out ----------
__global__ __launch_bounds__(512)
void gemm_out(const unsigned short* __restrict__ A,
              const unsigned short* __restrict__ Bw,
              float* __restrict__ Out, const float* __restrict__ Resid,
              int lda) {
    extern __shared__ __align__(16) char smem[];
    const int K = 1536, Nn = 768;

    const int tid = threadIdx.x;
    const int bid = blockIdx.x;
    const int xcd = bid & 7, local = bid >> 3;
    const int mt = xcd * 8 + local / 6;
    const int nt = local % 6;
    const int m0 = mt * 128, n0 = nt * 128;

    const int wave = tid >> 6, lane = tid & 63;
    const int wr = wave >> 2, wc = wave & 3;
    const int lr = lane & 15, q = lane >> 4;

    const int gl   = (lr & 7) << 4;
    const int arow = wr * 64 + lr;
    const int brow = wc * 32 + lr;
    const int colq = q << 4;

    const int srow  = tid >> 3;
    const int sslot = (tid & 7) ^ (srow & 7);
    const unsigned short* ga = A  + (size_t)(m0 + srow) * lda + sslot * 8;
    const unsigned short* gb = Bw + (size_t)(n0 + srow) * K   + sslot * 8;
    char* sAd = smem +         (size_t)tid * 16;
    char* sBd = smem + 32768 + (size_t)tid * 16;
    const size_t gstep_a = (size_t)64 * lda;
    const size_t gstep_b = (size_t)64 * K;

    f32x4 acc[4][2] = {};

    #pragma unroll
    for (int i = 0; i < 2; ++i) {
        load_lds16(ga + (size_t)i * gstep_a, sAd + i * 8192);
        load_lds16(gb + (size_t)i * gstep_b, sBd + i * 8192);
    }

    const int NT = K >> 6;   // 24
    for (int t = 0; t < NT; ++t) {
        const int d = t & 1;
        const bool more = (t + 1 < NT);
        if (more) {
            const size_t kg = (size_t)(t + 1) * 64;
            const int ld = (d ^ 1) * 16384;
            #pragma unroll
            for (int i = 0; i < 2; ++i) {
                load_lds16(ga + kg + (size_t)i * gstep_a, sAd + ld + i * 8192);
                load_lds16(gb + kg + (size_t)i * gstep_b, sBd + ld + i * 8192);
            }
            asm volatile("s_waitcnt vmcnt(4)" ::: "memory");
        } else {
            asm volatile("s_waitcnt vmcnt(0)" ::: "memory");
        }
        __builtin_amdgcn_s_barrier();

        const char* pa = smem +         d * 16384;
        const char* pb = smem + 32768 + d * 16384;
        #pragma unroll
        for (int kh = 0; kh < 2; ++kh) {
            const int col = ((kh << 6) | colq) ^ gl;
            bf16x8 af[4], bfr[2];
            #pragma unroll
            for (int m = 0; m < 4; ++m)
                af[m] = *(const bf16x8*)(pa + (arow + m * 16) * 128 + col);
            #pragma unroll
            for (int n = 0; n < 2; ++n)
                bfr[n] = *(const bf16x8*)(pb + (brow + n * 16) * 128 + col);

            __builtin_amdgcn_s_setprio(1);
            #pragma unroll
            for (int m = 0; m < 4; ++m)
                #pragma unroll
                for (int n = 0; n < 2; ++n)
                    acc[m][n] = __builtin_amdgcn_mfma_f32_16x16x32_bf16(af[m], bfr[n], acc[m][n], 0, 0, 0);
            __builtin_amdgcn_s_setprio(0);
        }
        __builtin_amdgcn_s_barrier();
    }

    #pragma unroll
    for (int m = 0; m < 4; ++m) {
        #pragma unroll
        for (int r = 0; r < 4; ++r) {
            int row = m0 + wr * 64 + m * 16 + q * 4 + r;
            #pragma unroll
            for (int n = 0; n < 2; ++n) {
                int col = n0 + wc * 32 + n * 16 + lr;
                Out[(size_t)row * Nn + col] = acc[m][n][r] + Resid[(size_t)row * Nn + col];
            }
        }
    }
}

// ---------- fused conv(4)+silu+layout ----------
__global__ __launch_bounds__(256)
void conv_fused_kernel(const unsigned short* __restrict__ zx,
                       const float* __restrict__ cw, const float* __restrict__ cb,
                       unsigned short* __restrict__ xT, unsigned short* __restrict__ bT,
                       unsigned short* __restrict__ Brow, unsigned short* __restrict__ Crow) {
    __shared__ unsigned short outt[64][66];
    __shared__ float cwl[64][4];
    __shared__ float cbl[64];

    int blk = blockIdx.x;
    int cht = blk % 28;
    int tt  = (blk / 28) % 32;
    int b   = blk / (28 * 32);
    int ch0 = cht * 64, t0 = tt * 64;
    int tid = threadIdx.x;
    int tx = tid & 63, ty = tid >> 6;

    if (tid < 64) cbl[tid] = cb[ch0 + tid];
    cwl[tid >> 2][tid & 3] = cw[(ch0 + (tid >> 2)) * 4 + (tid & 3)];
    __syncthreads();

    const unsigned short* zp = zx + (size_t)(b * 2048) * 3352 + 1536 + ch0 + tx;
    float w0 = cwl[tx][0], w1 = cwl[tx][1], w2 = cwl[tx][2], w3 = cwl[tx][3];
    float bias = cbl[tx];
    int tg = t0 + ty * 16;
    float r0 = (tg >= 3) ? bf2f(zp[(size_t)(tg - 3) * 3352]) : 0.f;
    float r1 = (tg >= 2) ? bf2f(zp[(size_t)(tg - 2) * 3352]) : 0.f;
    float r2 = (tg >= 1) ? bf2f(zp[(size_t)(tg - 1) * 3352]) : 0.f;
    #pragma unroll
    for (int k = 0; k < 16; ++k) {
        float cur = bf2f(zp[(size_t)(tg + k) * 3352]);
        float a = bias + r0 * w0 + r1 * w1 + r2 * w2 + cur * w3;
        a = a / (1.f + __expf(-a));        // silu (fast exp: bf16-bound)
        outt[ty * 16 + k][tx] = f2bf(a);
        r0 = r1; r1 = r2; r2 = cur;
    }
    __syncthreads();

    if (ch0 < 1536) {
        unsigned short* dst = xT + ((size_t)(b * 1536 + ch0)) * 2048 + t0;
        #pragma unroll
        for (int k = 0; k < 16; ++k) {
            int chl = ty * 16 + k;
            dst[(size_t)chl * 2048 + tx] = outt[tx][chl];
        }
    } else if (ch0 < 1664) {
        int n0 = ch0 - 1536;
        unsigned short* dstT = bT + ((size_t)(b * 128 + n0)) * 2048 + t0;
        #pragma unroll
        for (int k = 0; k < 16; ++k) {
            int chl = ty * 16 + k;
            dstT[(size_t)chl * 2048 + tx] = outt[tx][chl];
        }
        unsigned short* dstR = Brow + ((size_t)(b * 2048 + t0)) * 128 + n0;
        int tl = tid >> 3, c8 = (tid & 7) << 3;
        #pragma unroll
        for (int it = 0; it < 2; ++it) {
            int t = tl + it * 32;
            unsigned short tmp[8];
            #pragma unroll
            for (int jj = 0; jj < 8; ++jj) tmp[jj] = outt[t][c8 + jj];
            *(uint4*)(dstR + (size_t)t * 128 + c8) = *(uint4*)tmp;
        }
    } else {
        int n0 = ch0 - 1664;
        unsigned short* dstR = Crow + ((size_t)(b * 2048 + t0)) * 128 + n0;
        int tl = tid >> 3, c8 = (tid & 7) << 3;
        #pragma unroll
        for (int it = 0; it < 2; ++it) {
            int t = tl + it * 32;
            unsigned short tmp[8];
            #pragma unroll
            for (int jj = 0; jj < 8; ++jj) tmp[jj] = outt[t][c8 + jj];
            *(uint4*)(dstR + (size_t)t * 128 + c8) = *(uint4*)tmp;
        }
    }
}

// ---------- dt: 1024 blocks x 256 thr, 8 rows/block; x + w_dt staged in LDS; full f32 ----------
__global__ __launch_bounds__(256)
void dt_kernel(const float* __restrict__ x, const float* __restrict__ w_in,
               const float* __restrict__ dt_bias, const float* __restrict__ A_log,
               float2* __restrict__ dtdA) {
    __shared__ float xs[8 * 768];        // 24 KB
    __shared__ float wsh[24 * 257];      // 24.1 KB
    const int tid = threadIdx.x;
    const int row0 = blockIdx.x * 8;

    for (int i = tid; i < 8 * 768 / 4; i += 256)
        *(float4*)(xs + i * 4) = *(const float4*)(x + (size_t)row0 * 768 + (size_t)i * 4);

    const int rr = tid / 24, hh = tid - rr * 24;   // valid for tid < 192
    float acc0 = 0.f, acc1 = 0.f, acc2 = 0.f, acc3 = 0.f;

    for (int kc = 0; kc < 3; ++kc) {
        __syncthreads();
        for (int i = tid; i < 24 * 256; i += 256) {
            int h = i >> 8, kk = i & 255;
            wsh[h * 257 + kk] = w_in[(size_t)(3328 + h) * 768 + kc * 256 + kk];
        }
        __syncthreads();
        if (tid < 192) {
            const float* xp = xs + rr * 768 + kc * 256;
            const float* wp = wsh + hh * 257;
            #pragma unroll 16
            for (int kk = 0; kk < 256; kk += 4) {
                acc0 += xp[kk]     * wp[kk];
                acc1 += xp[kk + 1] * wp[kk + 1];
                acc2 += xp[kk + 2] * wp[kk + 2];
                acc3 += xp[kk + 3] * wp[kk + 3];
            }
        }
    }
    if (tid < 192) {
        float v = (acc0 + acc1) + (acc2 + acc3) + dt_bias[hh];
        float dt = (v > 20.f) ? v : log1pf(expf(v));   // exact libm: feeds f32 scan chain
        float A = -expf(A_log[hh]);
        dtdA[(size_t)(row0 + rr) * 24 + hh] = make_float2(dt, dt * A);   // (dt, log dA)
    }
}

// ---------- SSD local kernel: per (b,h,chunk): G -> M -> Y, s_out ----------
__global__ __launch_bounds__(256)
void ssd_local_kernel(const unsigned short* __restrict__ Brow,
                      const unsigned short* __restrict__ Crow,
                      const float2* __restrict__ dtdA,
                      const unsigned short* __restrict__ xT,
                      const unsigned short* __restrict__ bT,
                      const float* __restrict__ Dh,
                      unsigned short* __restrict__ yb,
                      unsigned short* __restrict__ sst,
                      float* __restrict__ Pbuf) {
    extern __shared__ __align__(16) char smem[];
    __bf16* Bs  = (__bf16*)smem;                 // 128 x SLD; later Xt(0:17408)+Xtw(17408:34816)
    __bf16* Cs  = (__bf16*)(smem + 34816);       // 128 x SLD; later Ms
    float*  Lc  = (float*)(smem + 69632);        // 128
    float*  dtl = (float*)(smem + 70144);        // 128

    const int tid = threadIdx.x;
    const int c   = blockIdx.x & 15;
    const int bh  = blockIdx.x >> 4;
    const int b   = bh / 24, h = bh % 24;
    const int t0g = b * 2048 + c * QCHUNK;
    const int wave = tid >> 6, lane = tid & 63;
    const int lr = lane & 15, q = lane >> 4;

    for (int cc = tid; cc < 2048; cc += 256) {
        int r = cc >> 4, c8 = (cc & 15) << 3;
        *(uint4*)(Bs + r * SLD + c8) = *(const uint4*)(Brow + ((size_t)(t0g + r)) * 128 + c8);
        *(uint4*)(Cs + r * SLD + c8) = *(const uint4*)(Crow + ((size_t)(t0g + r)) * 128 + c8);
    }
    if (tid < 128) {
        float2 dd = dtdA[((size_t)t0g + tid) * 24 + h];
        dtl[tid] = dd.x;
        Lc[tid]  = dd.y;     // log dA
    }
    __syncthreads();
    // single-wave pair scan
    if (tid < 64) {
        float a0 = Lc[2 * tid], a1 = Lc[2 * tid + 1];
        float s = a0 + a1;
        #pragma unroll
        for (int d = 1; d < 64; d <<= 1) {
            float v = __shfl_up(s, d);
            if (tid >= d) s += v;
        }
        float ex = s - (a0 + a1);
        Lc[2 * tid]     = ex + a0;
        Lc[2 * tid + 1] = ex + a0 + a1;
    }
    __syncthreads();

    // P1: G = Cs . Bs^T
    const int wm = (wave & 1) * 64, wn = (wave >> 1) * 64;
    f32x4 g[4][4] = {};
    #pragma unroll
    for (int k0 = 0; k0 < 128; k0 += 32) {
        bf16x8 af[4], bfr[4];
        #pragma unroll
        for (int t = 0; t < 4; ++t) {
            af[t]  = *(const bf16x8*)(Cs + (wm + t * 16 + lr) * SLD + k0 + q * 8);
            bfr[t] = *(const bf16x8*)(Bs + (wn + t * 16 + lr) * SLD + k0 + q * 8);
        }
        #pragma unroll
        for (int ti = 0; ti < 4; ++ti)
            #pragma unroll
            for (int tj = 0; tj < 4; ++tj)
                g[ti][tj] = __builtin_amdgcn_mfma_f32_16x16x32_bf16(af[ti], bfr[tj], g[ti][tj], 0, 0, 0);
    }
    __syncthreads();

    // P5: masked scale -> Ms[t][tau]  (fast exp: output is bf16)
    __bf16* Ms = Cs;
    {
        float lt_[4], dt_[4];
        #pragma unroll
        for (int tj = 0; tj < 4; ++tj) {
            int tau = wn + tj * 16 + lr;
            lt_[tj] = Lc[tau];
            dt_[tj] = dtl[tau];
        }
        #pragma unroll
        for (int ti = 0; ti < 4; ++ti) {
            #pragma unroll
            for (int r = 0; r < 4; ++r) {
                int t = wm + ti * 16 + q * 4 + r;
                float Lt = Lc[t];
                #pragma unroll
                for (int tj = 0; tj < 4; ++tj) {
                    int tau = wn + tj * 16 + lr;
                    float mv = (tau <= t) ? g[ti][tj][r] * __expf(Lt - lt_[tj]) * dt_[tj] : 0.f;
                    unsigned short u = f2bf(mv);
                    Ms[t * SLD + tau] = *(__bf16*)&u;
                }
            }
        }
    }

    // P3: stage Xt[p][t] and Xtw[p][t]
    __bf16* Xt  = Bs;
    __bf16* Xtw = (__bf16*)(smem + 17408);
    {
        float LQ = Lc[127];
        const unsigned short* xTb = xT + ((size_t)(b * 1536 + h * 64)) * 2048 + c * QCHUNK;
        for (int cc = tid; cc < 1024; cc += 256) {
            int p = cc >> 4, c8 = (cc & 15) << 3;
            uint4 v = *(const uint4*)(xTb + (size_t)p * 2048 + c8);
            *(uint4*)(Xt + p * SLD + c8) = v;
            unsigned short uu[8] = {(unsigned short)(v.x & 0xFFFF), (unsigned short)(v.x >> 16),
                                    (unsigned short)(v.y & 0xFFFF), (unsigned short)(v.y >> 16),
                                    (unsigned short)(v.z & 0xFFFF), (unsigned short)(v.z >> 16),
                                    (unsigned short)(v.w & 0xFFFF), (unsigned short)(v.w >> 16)};
            float w0[8];
            #pragma unroll
            for (int jj = 0; jj < 8; ++jj) {
                int tau = c8 + jj;
                w0[jj] = bf2f(uu[jj]) * __expf(LQ - Lc[tau]) * dtl[tau];
            }
            *(uint4*)(Xtw + p * SLD + c8) = pack8(make_float4(w0[0], w0[1], w0[2], w0[3]),
                                                  make_float4(w0[4], w0[5], w0[6], w0[7]));
        }
    }
    __syncthreads();

    // P4: s_out[n][p] = bT . Xtw^T
    {
        f32x4 so[2][4] = {};
        const unsigned short* bTb = bT + ((size_t)(b * 128)) * 2048 + c * QCHUNK;
        #pragma unroll
        for (int k0 = 0; k0 < 128; k0 += 32) {
            bf16x8 af[2], bfr[4];
            #pragma unroll
            for (int ti = 0; ti < 2; ++ti) {
                int n = wave * 32 + ti * 16 + lr;
                af[ti] = *(const bf16x8*)(bTb + (size_t)n * 2048 + k0 + q * 8);
            }
            #pragma unroll
            for (int tj = 0; tj < 4; ++tj)
                bfr[tj] = *(const bf16x8*)(Xtw + (tj * 16 + lr) * SLD + k0 + q * 8);
            #pragma unroll
            for (int ti = 0; ti < 2; ++ti)
                #pragma unroll
                for (int tj = 0; tj < 4; ++tj)
                    so[ti][tj] = __builtin_amdgcn_mfma_f32_16x16x32_bf16(af[ti], bfr[tj], so[ti][tj], 0, 0, 0);
        }
        unsigned short* sb = sst + ((size_t)(bh * NCHUNK + c)) * 8192;
        #pragma unroll
        for (int ti = 0; ti < 2; ++ti) {
            #pragma unroll
            for (int r = 0; r < 4; ++r) {
                int n = wave * 32 + ti * 16 + q * 4 + r;
                #pragma unroll
                for (int tj = 0; tj < 4; ++tj) {
                    int p = tj * 16 + lr;
                    sb[n * 64 + p] = f2bf(so[ti][tj][r]);
                }
            }
        }
        if (tid == 0) Pbuf[bh * NCHUNK + c] = __expf(Lc[127]);
    }

    // P6: Y[t][p] = Ms . Xt^T  (+ D skip) -> bf16
    {
        f32x4 ya[2][4] = {};
        #pragma unroll
        for (int k0 = 0; k0 < 128; k0 += 32) {
            bf16x8 af[2], bfr[4];
            #pragma unroll
            for (int ti = 0; ti < 2; ++ti)
                af[ti] = *(const bf16x8*)(Ms + (wave * 32 + ti * 16 + lr) * SLD + k0 + q * 8);
            #pragma unroll
            for (int tj = 0; tj < 4; ++tj)
                bfr[tj] = *(const bf16x8*)(Xt + (tj * 16 + lr) * SLD + k0 + q * 8);
            #pragma unroll
            for (int ti = 0; ti < 2; ++ti)
                #pragma unroll
                for (int tj = 0; tj < 4; ++tj)
                    ya[ti][tj] = __builtin_amdgcn_mfma_f32_16x16x32_bf16(af[ti], bfr[tj], ya[ti][tj], 0, 0, 0);
        }
        float Dv = Dh[h];
        unsigned short* ybb = yb + (size_t)t0g * 1536 + h * 64;
        #pragma unroll
        for (int ti = 0; ti < 2; ++ti) {
            #pragma unroll
            for (int r = 0; r < 4; ++r) {
                int t = wave * 32 + ti * 16 + q * 4 + r;
                #pragma unroll
                for (int tj = 0; tj < 4; ++tj) {
                    int p = tj * 16 + lr;
                    __bf16 xb = Xt[p * SLD + t];
                    float xv = bf2f(*(unsigned short*)&xb);
                    ybb[(size_t)t * 1536 + p] = f2bf(ya[ti][tj][r] + Dv * xv);
                }
            }
        }
    }
}

// ---------- combine: per-(bh, 32-p-slice) block; scan in registers, LDS transpose ----------
__global__ __launch_bounds__(256)
void combine_kernel(const unsigned short* __restrict__ sst,
                    unsigned short* __restrict__ sstT,
                    const float* __restrict__ Pbuf) {
    __shared__ unsigned short tl[32 * 130];        // [p-local 32][n 128], pad to 130
    const int blk = blockIdx.x;                    // 192 = 96 bh x 2 p-halves
    const int bh = blk >> 1;
    const int ph = (blk & 1) * 32;
    const int tid = threadIdx.x;
    const int pl = tid & 31;
    const int nb = tid >> 5;
    const unsigned short* sb = sst + (size_t)bh * NCHUNK * 8192;
    unsigned short* tb = sstT + (size_t)bh * NCHUNK * 8192 + ph * 128;
    const float* Pb = Pbuf + bh * NCHUNK;

    float s[16];
    #pragma unroll
    for (int i = 0; i < 16; ++i) s[i] = 0.f;

    for (int c = 0; c < NCHUNK; ++c) {
        const float Pc = Pb[c];
        const unsigned short* sc = sb + (size_t)c * 8192;
        #pragma unroll
        for (int i = 0; i < 16; ++i) {
            int n = nb + 8 * i;
            unsigned short v = sc[n * 64 + ph + pl];
            tl[pl * 130 + n] = f2bf(s[i]);
            s[i] = Pc * s[i] + bf2f(v);
        }
        __syncthreads();
        uint* tlw = (uint*)tl;
        uint4* tc4 = (uint4*)(tb + (size_t)c * 8192);
        #pragma unroll
        for (int k = 0; k < 2; ++k) {
            int j = tid + k * 256;
            int pp = j >> 4;
            int w0 = pp * 65 + (j & 15) * 4;
            tc4[j] = make_uint4(tlw[w0], tlw[w0 + 1], tlw[w0 + 2], tlw[w0 + 3]);
        }
        __syncthreads();
    }
}

// ---------- SSD inter kernel (yb bf16 RMW) ----------
__global__ __launch_bounds__(256)
void ssd_inter_kernel(const unsigned short* __restrict__ Crow,
                      const float2* __restrict__ dtdA,
                      const unsigned short* __restrict__ sstT,
                      unsigned short* __restrict__ yb) {
    __shared__ __align__(16) __bf16 Cs[128 * SLD];
    __shared__ __align__(16) __bf16 St[64 * SLD];
    __shared__ float Lc[128];

    const int tid = threadIdx.x;
    const int blk = blockIdx.x;
    const int bh = blk / 15;
    const int c  = blk % 15 + 1;
    const int b = bh / 24, h = bh % 24;
    const int t0g = b * 2048 + c * QCHUNK;
    const int wave = tid >> 6, lane = tid & 63;
    const int lr = lane & 15, q = lane >> 4;

    for (int cc = tid; cc < 2048; cc += 256) {
        int r = cc >> 4, c8 = (cc & 15) << 3;
        *(uint4*)(Cs + r * SLD + c8) = *(const uint4*)(Crow + ((size_t)(t0g + r)) * 128 + c8);
    }
    const unsigned short* stb = sstT + ((size_t)(bh * NCHUNK + c)) * 8192;
    for (int cc = tid; cc < 1024; cc += 256) {
        int p = cc >> 4, c8 = (cc & 15) << 3;
        *(uint4*)(St + p * SLD + c8) = *(const uint4*)(stb + p * 128 + c8);
    }
    if (tid < 128) Lc[tid] = dtdA[((size_t)t0g + tid) * 24 + h].y;
    __syncthreads();
    // single-wave pair scan
    if (tid < 64) {
        float a0 = Lc[2 * tid], a1 = Lc[2 * tid + 1];
        float s = a0 + a1;
        #pragma unroll
        for (int d = 1; d < 64; d <<= 1) {
            float v = __shfl_up(s, d);
            if (tid >= d) s += v;
        }
        float ex = s - (a0 + a1);
        Lc[2 * tid]     = ex + a0;
        Lc[2 * tid + 1] = ex + a0 + a1;
    }
    __syncthreads();

    f32x4 ya[2][4] = {};
    #pragma unroll
    for (int k0 = 0; k0 < 128; k0 += 32) {
        bf16x8 af[2], bfr[4];
        #pragma unroll
        for (int ti = 0; ti < 2; ++ti)
            af[ti] = *(const bf16x8*)(Cs + (wave * 32 + ti * 16 + lr) * SLD + k0 + q * 8);
        #pragma unroll
        for (int tj = 0; tj < 4; ++tj)
            bfr[tj] = *(const bf16x8*)(St + (tj * 16 + lr) * SLD + k0 + q * 8);
        #pragma unroll
        for (int ti = 0; ti < 2; ++ti)
            #pragma unroll
            for (int tj = 0; tj < 4; ++tj)
                ya[ti][tj] = __builtin_amdgcn_mfma_f32_16x16x32_bf16(af[ti], bfr[tj], ya[ti][tj], 0, 0, 0);
    }
    unsigned short* ybb = yb + (size_t)t0g * 1536 + h * 64;
    #pragma unroll
    for (int ti = 0; ti < 2; ++ti) {
        #pragma unroll
        for (int r = 0; r < 4; ++r) {
            int t = wave * 32 + ti * 16 + q * 4 + r;
            float sc = __expf(Lc[t]);
            #pragma unroll
            for (int tj = 0; tj < 4; ++tj) {
                int p = tj * 16 + lr;
                unsigned short* yp = ybb + (size_t)t * 1536 + p;
                *yp = f2bf(bf2f(*yp) + sc * ya[ti][tj][r]);
            }
        }
    }
}

// ---------- gated RMSNorm: reads yb bf16, writes bf16 into zx cols [1536,3072) ----------
__global__ __launch_bounds__(256)
void norm_kernel(const unsigned short* __restrict__ yb,
                 unsigned short* __restrict__ zx,
                 const float* __restrict__ nw) {
    int row = blockIdx.x;
    const unsigned short* yr = yb + (size_t)row * 1536;
    unsigned short* zr = zx + (size_t)row * 3352;
    int tid = threadIdx.x;
    float u[6];
    float ss = 0.f;
    #pragma unroll
    for (int i = 0; i < 6; ++i) {
        int c = tid + i * 256;
        float z = bf2f(zr[c]);
        float uu = bf2f(yr[c]) * (z / (1.f + __expf(-z)));
        u[i] = uu;
        ss += uu * uu;
    }
    #pragma unroll
    for (int m = 1; m < 64; m <<= 1) ss += __shfl_xor(ss, m);
    __shared__ float red[4];
    if ((tid & 63) == 0) red[tid >> 6] = ss;
    __syncthreads();
    float tot = red[0] + red[1] + red[2] + red[3];
    float inv = rsqrtf(tot * (1.f / 1536.f) + 1e-5f);
    #pragma unroll
    for (int i = 0; i < 6; ++i) {
        int c = tid + i * 256;
        zr[1536 + c] = f2bf(u[i] * inv * nw[c]);
    }
}

// ---------- launch ----------
extern "C" void kernel_launch(void* const* d_in, const int* in_sizes, int n_in,
                              void* d_out, int out_size, void* d_ws, size_t ws_size,
                              hipStream_t stream) {
    const float* x       = (const float*)d_in[0];
    const float* w_in    = (const float*)d_in[1];
    const float* conv_w  = (const float*)d_in[2];
    const float* conv_b  = (const float*)d_in[3];
    const float* dt_bias = (const float*)d_in[4];
    const float* A_log   = (const float*)d_in[5];
    const float* Dp      = (const float*)d_in[6];
    const float* nw      = (const float*)d_in[7];
    const float* w_out   = (const float*)d_in[8];
    float* out = (float*)d_out;

    char* ws = (char*)d_ws;
    const size_t off_zx   = 0;                        // 8192*3352 bf16 = 54,919,168
    const size_t off_A    = off_zx + 54919168;        // region A (58,720,256 reserved)
    const size_t off_xT   = off_A;                    // 25,165,824 (sstT aliases later)
    const size_t off_bT   = off_A + 25165824;         // 2,097,152
    const size_t off_Brow = off_A + 27262976;         // 2,097,152
    const size_t off_Crow = off_A + 29360128;         // 2,097,152
    const size_t off_dtdA = off_A + 58720256;         // 1,572,864
    const size_t off_y    = off_dtdA + 1572864;       // 50,331,648 reserved: yb bf16 (25MB) + w_out_bf; x_bf aliases head
    const size_t off_sst  = off_y + 50331648;         // 25,165,824 (w_in_bf aliases head)
    const size_t off_P    = off_sst + 25165824;       // 6,144

    unsigned short* zx   = (unsigned short*)(ws + off_zx);
    unsigned short* xT   = (unsigned short*)(ws + off_xT);
    unsigned short* bT   = (unsigned short*)(ws + off_bT);
    unsigned short* Brow = (unsigned short*)(ws + off_Brow);
    unsigned short* Crow = (unsigned short*)(ws + off_Crow);
    float2* dtdA = (float2*)(ws + off_dtdA);
    unsigned short* yb   = (unsigned short*)(ws + off_y);
    unsigned short* sst  = (unsigned short*)(ws + off_sst);
    unsigned short* sstT = xT;                        // xT dead after ssd_local
    float* Pbuf = (float*)(ws + off_P);

    // transient aliases (dead regions at time of use)
    unsigned short* x_bf     = (unsigned short*)(ws + off_y);              // gemm1 only (before yb written)
    unsigned short* w_out_bf = (unsigned short*)(ws + off_y + 25165824);   // second half of off_y region
    unsigned short* w_in_bf  = (unsigned short*)(ws + off_sst);            // gemm1 only (before sst written)

    static bool attr_set = false;
    if (!attr_set) {
        hipFuncSetAttribute((const void*)ssd_local_kernel,
                            hipFuncAttributeMaxDynamicSharedMemorySize, 70656);
        hipFuncSetAttribute((const void*)gemm_8phase,
                            hipFuncAttributeMaxDynamicSharedMemorySize, 131072);
        hipFuncSetAttribute((const void*)gemm_out,
                            hipFuncAttributeMaxDynamicSharedMemorySize, 65536);
        attr_set = true;
    }

    // 0. convert x, w_in rows [0,3328), w_out -> bf16 (one launch)
    convert_kernel<<<4896, 256, 0, stream>>>(x, w_in, w_out, x_bf, w_in_bf, w_out_bf);
    // 1. in_proj (M=8192, N=3328 = 13x256 exactly), out stride 3352
    gemm_8phase<<<416, 512, 131072, stream>>>(x_bf, w_in_bf, zx, 3352, 768);
    // 2. fused conv + silu + layout
    conv_fused_kernel<<<3584, 256, 0, stream>>>(zx, conv_w, conv_b, xT, bT, Brow, Crow);
    // 3. dt / log-dA (full f32) — LDS-staged, 8 rows/block
    dt_kernel<<<1024, 256, 0, stream>>>(x, w_in, dt_bias, A_log, dtdA);
    // 4. SSD local (yb bf16, fast-exp)
    ssd_local_kernel<<<1536, 256, 70656, stream>>>(Brow, Crow, dtdA, xT, bT, Dp, yb, sst, Pbuf);
    // 5. combine (R11 split form — 192 blocks but tiny; fused variant was occupancy-bound)
    combine_kernel<<<192, 256, 0, stream>>>(sst, sstT, Pbuf);
    // 6. SSD inter (1440 blocks, yb bf16 RMW)
    ssd_inter_kernel<<<1440, 256, 0, stream>>>(Crow, dtdA, sstT, yb);
    // 7. gated RMSNorm (yb bf16 in) -> bf16 into zx cols [1536,3072)
    norm_kernel<<<8192, 256, 0, stream>>>(yb, zx, nw);
    // 8. out_proj + residual
    gemm_out<<<384, 512, 65536, stream>>>(zx + 1536, w_out_bf, out, x, 3352);
}